// Round 6
// baseline (872.587 us; speedup 1.0000x reference)
//
#include <hip/hip_runtime.h>
#include <hip/hip_bf16.h>
#include <hip/hip_cooperative_groups.h>

namespace cg = cooperative_groups;

// Problem constants
#define B_    8
#define C_    64
#define P_    64
#define H_    256
#define W_    256
#define BHW_  (B_ * H_ * W_)   // 524288
#define BN_EPS 1e-5f

#define CHUNK 16
#define SWC   64               // LDS row stride (floats)

// DPP lane shifts within 16-lane rows (seg dimension = low 4 lane bits).
__device__ __forceinline__ float dpp_row_shr1(float v) {   // lane n <- n-1
    return __int_as_float(__builtin_amdgcn_update_dpp(
        0, __float_as_int(v), 0x111, 0xF, 0xF, true));
}
__device__ __forceinline__ float dpp_row_shl1(float v) {   // lane n <- n+1
    return __int_as_float(__builtin_amdgcn_update_dpp(
        0, __float_as_int(v), 0x101, 0xF, 0xF, true));
}

// ---------------------------------------------------------------------------
// Cooperative mega-kernel: all 64 chain steps in ONE launch; grid.sync()
// between the 4 16-channel chunks (replaces 3 kernel-launch boundaries).
// 512 blocks x 1024 threads, <=64 VGPR (launch_bounds) and 2x33.8 KB LDS
// -> exactly 2 blocks/CU co-resident, satisfying cooperative-launch checks.
// Block 0 additionally precomputes the BN-folded A matrix + bias + cw into
// prep_out (read by fuse2 after this kernel completes).
// ---------------------------------------------------------------------------
__global__ __launch_bounds__(1024, 8) void chain_coop(
    const float* __restrict__ x,
    const float* __restrict__ dw_w,
    float* __restrict__ ys,
    const float* __restrict__ pw_w,
    const float* __restrict__ gamma,
    const float* __restrict__ beta,
    const float* __restrict__ mean,
    const float* __restrict__ var,
    const float* __restrict__ conv_w,
    float* __restrict__ prep_out,    // As[4096] | bias[64] | cw[64]
    int do_prep)
{
    cg::grid_group grid = cg::this_grid();

    __shared__ __align__(16) float buf0[66 * SWC];
    __shared__ __align__(16) float buf1[66 * SWC];

    const int tid = threadIdx.x;
    const int row = tid >> 4;          // 0..63
    const int seg = tid & 15;          // 0..15
    const int lx  = seg * 4;           // 0..60
    const int b   = blockIdx.z;
    const int ty0 = blockIdx.y * 32;
    const int tx0 = blockIdx.x * 32;
    const int gy  = ty0 - 16 + row;
    const int gx  = tx0 - 16 + lx;
    const bool inImg = (gy >= 0) && (gy < H_) && (gx >= 0) && (gx < W_);
    const float msk = inImg ? 1.0f : 0.0f;
    const int cell = (row + 1) * SWC + lx;
    const bool wOK = (row >= 16) && (row < 48) && (seg >= 4) && (seg < 12);
    const long long goff = (long long)(b * H_ + gy) * W_ + gx; // may be <0; only
                                                               // deref'd if wOK

    if (do_prep && blockIdx.x == 0 && blockIdx.y == 0 && blockIdx.z == 0) {
        for (int idx = tid; idx < C_ * P_; idx += 1024) {
            int p = idx & 63;
            int c = idx >> 6;
            float sc = gamma[p] / sqrtf(var[p] + BN_EPS);
            prep_out[idx] = pw_w[p * C_ + c] * sc;       // As[c][p]
        }
        if (tid < P_) {
            float sc = gamma[tid] / sqrtf(var[tid] + BN_EPS);
            prep_out[4096 + tid] = beta[tid] - mean[tid] * sc;
            prep_out[4160 + tid] = conv_w[tid];
        }
    }

    if (row == 0) {                    // zero pad rows once (persist all chunks)
        float4 z = make_float4(0.f, 0.f, 0.f, 0.f);
        *(float4*)&buf0[lx] = z;  *(float4*)&buf0[65 * SWC + lx] = z;
        *(float4*)&buf1[lx] = z;  *(float4*)&buf1[65 * SWC + lx] = z;
    }

    for (int k = 0; k < C_ / CHUNK; ++k) {
        // seed: chunk 0 from x[:,0]; chunk k from ys channel 16k-1
        const float* in = (k == 0)
            ? x + (size_t)b * (C_ * H_ * W_)
            : ys + (size_t)(CHUNK * k - 1) * BHW_ + (size_t)b * (H_ * W_);
        float4 v = make_float4(0.f, 0.f, 0.f, 0.f);
        if (inImg)
            v = *(const float4*)(in + (size_t)gy * W_ + gx);

        float* cur = buf0;
        float* nxt = buf1;
        *(float4*)&cur[cell] = v;
        __syncthreads();

        const float* dwk = dw_w + k * (CHUNK * 9);

#pragma unroll
        for (int i = 0; i < CHUNK; ++i) {
            const float w0 = dwk[i*9+0], w1 = dwk[i*9+1], w2 = dwk[i*9+2];
            const float w3 = dwk[i*9+3], w4 = dwk[i*9+4], w5 = dwk[i*9+5];
            const float w6 = dwk[i*9+6], w7 = dwk[i*9+7], w8 = dwk[i*9+8];

            float4 rT = *(const float4*)&cur[cell - SWC];
            float4 rM = *(const float4*)&cur[cell];
            float4 rB = *(const float4*)&cur[cell + SWC];

            float tl = dpp_row_shr1(rT.w), tr = dpp_row_shl1(rT.x);
            float ml = dpp_row_shr1(rM.w), mr = dpp_row_shl1(rM.x);
            float bl = dpp_row_shr1(rB.w), br = dpp_row_shl1(rB.x);

            float s0 = fmaf(tl,   w0, fmaf(rT.x, w1, fmaf(rT.y, w2,
                       fmaf(ml,   w3, fmaf(rM.x, w4, fmaf(rM.y, w5,
                       fmaf(bl,   w6, fmaf(rB.x, w7, rB.y * w8))))))));
            float s1 = fmaf(rT.x, w0, fmaf(rT.y, w1, fmaf(rT.z, w2,
                       fmaf(rM.x, w3, fmaf(rM.y, w4, fmaf(rM.z, w5,
                       fmaf(rB.x, w6, fmaf(rB.y, w7, rB.z * w8))))))));
            float s2 = fmaf(rT.y, w0, fmaf(rT.z, w1, fmaf(rT.w, w2,
                       fmaf(rM.y, w3, fmaf(rM.z, w4, fmaf(rM.w, w5,
                       fmaf(rB.y, w6, fmaf(rB.z, w7, rB.w * w8))))))));
            float s3 = fmaf(rT.z, w0, fmaf(rT.w, w1, fmaf(tr,   w2,
                       fmaf(rM.z, w3, fmaf(rM.w, w4, fmaf(mr,   w5,
                       fmaf(rB.z, w6, fmaf(rB.w, w7, br   * w8))))))));
            float4 ov;
            ov.x = fminf(fmaxf(s0, 0.f), 6.f) * msk;
            ov.y = fminf(fmaxf(s1, 0.f), 6.f) * msk;
            ov.z = fminf(fmaxf(s2, 0.f), 6.f) * msk;
            ov.w = fminf(fmaxf(s3, 0.f), 6.f) * msk;

            if (i < CHUNK - 1) {
                *(float4*)&nxt[cell] = ov;
                __syncthreads();
                float* tmp = cur; cur = nxt; nxt = tmp;
            }
            if (wOK)
                *(float4*)(ys + (size_t)(CHUNK * k + i) * BHW_ + goff) = ov;
        }

        if (k < C_ / CHUNK - 1) {
            __threadfence();           // make ys stores device-visible
            grid.sync();
        }
    }
}

// ---------------------------------------------------------------------------
// Fuse v2: A/bias/cw come from global via UNIFORM addresses -> scalar loads
// (s_load) feeding v_fma scalar operands. Zero LDS traffic; VALU-bound.
// 1 px/thread for load-latency hiding (h[64] accumulators).
// ---------------------------------------------------------------------------
__global__ __launch_bounds__(256) void fuse2(
    const float* __restrict__ ys,      // (C, BHW)
    const float* __restrict__ prep,    // As[4096] | bias[64] | cw[64]
    float* __restrict__ out)           // (BHW)
{
    const size_t n = (size_t)blockIdx.x * 256 + threadIdx.x;

    float h[P_];
#pragma unroll
    for (int p = 0; p < P_; ++p) h[p] = 0.f;

#pragma unroll 4
    for (int c = 0; c < C_; ++c) {
        float y = ys[(size_t)c * BHW_ + n];
        const float* a = prep + c * P_;       // uniform address -> s_load
#pragma unroll
        for (int p = 0; p < P_; ++p)
            h[p] = fmaf(a[p], y, h[p]);
    }

    const float* bias = prep + 4096;
    const float* cw   = prep + 4160;
    float acc = 0.f;
#pragma unroll
    for (int p = 0; p < P_; ++p) {
        float v = fminf(fmaxf(h[p] + bias[p], 0.f), 6.f);
        acc = fmaf(cw[p], v, acc);
    }
    out[n] = acc;
}

// ---------------------------------------------------------------------------
// Fallback fuse (LDS A) — used only if ws_size can't fit the prep region.
// ---------------------------------------------------------------------------
__global__ __launch_bounds__(256) void fuse_kernel(
    const float* __restrict__ ys,
    const float* __restrict__ pw_w,
    const float* __restrict__ gamma,
    const float* __restrict__ beta,
    const float* __restrict__ mean,
    const float* __restrict__ var,
    const float* __restrict__ conv_w,
    float* __restrict__ out)
{
    __shared__ float As[C_ * P_];
    __shared__ float bias_s[P_];
    __shared__ float cw_s[P_];

    const int tid = threadIdx.x;
    for (int idx = tid; idx < C_ * P_; idx += 256) {
        int p = idx & 63;
        int c = idx >> 6;
        float scale = gamma[p] / sqrtf(var[p] + BN_EPS);
        As[idx] = pw_w[p * C_ + c] * scale;
    }
    if (tid < P_) {
        float scale = gamma[tid] / sqrtf(var[tid] + BN_EPS);
        bias_s[tid] = beta[tid] - mean[tid] * scale;
        cw_s[tid]   = conv_w[tid];
    }
    __syncthreads();

    const size_t n0 = (size_t)blockIdx.x * 512 + tid;
    const size_t n1 = n0 + 256;
    float h0[P_], h1[P_];
#pragma unroll
    for (int p = 0; p < P_; ++p) { h0[p] = 0.f; h1[p] = 0.f; }
#pragma unroll 2
    for (int c = 0; c < C_; ++c) {
        float y0 = ys[(size_t)c * BHW_ + n0];
        float y1 = ys[(size_t)c * BHW_ + n1];
        const float* arow = &As[c * P_];
#pragma unroll
        for (int p = 0; p < P_; ++p) {
            float av = arow[p];
            h0[p] = fmaf(av, y0, h0[p]);
            h1[p] = fmaf(av, y1, h1[p]);
        }
    }
    float acc0 = 0.f, acc1 = 0.f;
#pragma unroll
    for (int p = 0; p < P_; ++p) {
        float v0 = fminf(fmaxf(h0[p] + bias_s[p], 0.f), 6.f);
        float v1 = fminf(fmaxf(h1[p] + bias_s[p], 0.f), 6.f);
        acc0 = fmaf(cw_s[p], v0, acc0);
        acc1 = fmaf(cw_s[p], v1, acc1);
    }
    out[n0] = acc0;
    out[n1] = acc1;
}

// ---------------------------------------------------------------------------
extern "C" void kernel_launch(void* const* d_in, const int* in_sizes, int n_in,
                              void* d_out, int out_size, void* d_ws, size_t ws_size,
                              hipStream_t stream) {
    const float* x      = (const float*)d_in[0];
    const float* dw_w   = (const float*)d_in[1];
    const float* pw_w   = (const float*)d_in[2];
    const float* gamma  = (const float*)d_in[3];
    const float* beta   = (const float*)d_in[4];
    const float* mean   = (const float*)d_in[5];
    const float* var    = (const float*)d_in[6];
    const float* conv_w = (const float*)d_in[7];
    float* out = (float*)d_out;

    float* ys = (float*)d_ws;                          // 128 MiB
    const size_t ys_bytes = (size_t)C_ * BHW_ * sizeof(float);
    const bool big = ws_size >= ys_bytes + 17 * 1024;
    float* prep = (float*)((char*)d_ws + ys_bytes);
    int do_prep = big ? 1 : 0;

    void* kargs[] = {
        (void*)&x, (void*)&dw_w, (void*)&ys, (void*)&pw_w, (void*)&gamma,
        (void*)&beta, (void*)&mean, (void*)&var, (void*)&conv_w,
        (void*)&prep, (void*)&do_prep
    };
    hipLaunchCooperativeKernel(chain_coop, dim3(8, 8, 8), dim3(1024, 1, 1),
                               kargs, 0u, stream);

    if (big)
        fuse2<<<BHW_ / 256, 256, 0, stream>>>(ys, prep, out);
    else
        fuse_kernel<<<BHW_ / 512, 256, 0, stream>>>(
            ys, pw_w, gamma, beta, mean, var, conv_w, out);
}

// Round 7
// 273.797 us; speedup vs baseline: 3.1870x; 3.1870x over previous
//
#include <hip/hip_runtime.h>
#include <hip/hip_bf16.h>

// Problem constants
#define B_    8
#define C_    64
#define P_    64
#define H_    256
#define W_    256
#define BHW_  (B_ * H_ * W_)   // 524288
#define BN_EPS 1e-5f

#define CHUNK 16
#define SWC   64               // chain LDS row stride (floats)

// DPP lane shifts within 16-lane rows (seg dimension = low 4 lane bits).
__device__ __forceinline__ float dpp_row_shr1(float v) {   // lane n <- n-1
    return __int_as_float(__builtin_amdgcn_update_dpp(
        0, __float_as_int(v), 0x111, 0xF, 0xF, true));
}
__device__ __forceinline__ float dpp_row_shl1(float v) {   // lane n <- n+1
    return __int_as_float(__builtin_amdgcn_update_dpp(
        0, __float_as_int(v), 0x101, 0xF, 0xF, true));
}

// bf16 helpers (RNE)
__device__ __forceinline__ short f2bf(float x) {
    unsigned u = __float_as_uint(x);
    unsigned r = (u + 0x7FFFu + ((u >> 16) & 1u)) >> 16;
    return (short)r;
}
__device__ __forceinline__ float bf2f(short h) {
    return __uint_as_float(((unsigned)(unsigned short)h) << 16);
}

typedef __attribute__((ext_vector_type(8))) short bf16x8;
typedef __attribute__((ext_vector_type(4))) float f32x4;

// ---------------------------------------------------------------------------
// Chain kernel — EXACT R5 form (best measured). 16 steps/launch, 4 launches.
// ---------------------------------------------------------------------------
__global__ __launch_bounds__(1024, 8) void chain_kernel(
    const float* __restrict__ src,
    size_t src_batch_stride,
    const float* __restrict__ dw,
    float* __restrict__ ys,
    int c0)
{
    __shared__ __align__(16) float buf0[66 * SWC];
    __shared__ __align__(16) float buf1[66 * SWC];

    const int tid = threadIdx.x;
    const int row = tid >> 4;
    const int seg = tid & 15;
    const int lx  = seg * 4;
    const int b   = blockIdx.z;
    const int ty0 = blockIdx.y * 32;
    const int tx0 = blockIdx.x * 32;
    const int gy  = ty0 - 16 + row;
    const int gx  = tx0 - 16 + lx;
    const bool inImg = (gy >= 0) && (gy < H_) && (gx >= 0) && (gx < W_);
    const float msk = inImg ? 1.0f : 0.0f;

    float4 v = make_float4(0.f, 0.f, 0.f, 0.f);
    if (inImg)
        v = *(const float4*)(src + (size_t)b * src_batch_stride
                             + (size_t)gy * W_ + gx);

    float* cur = buf0;
    float* nxt = buf1;
    const int cell = (row + 1) * SWC + lx;
    *(float4*)&cur[cell] = v;
    if (row == 0) {
        float4 z = make_float4(0.f, 0.f, 0.f, 0.f);
        *(float4*)&buf0[lx] = z;  *(float4*)&buf0[65 * SWC + lx] = z;
        *(float4*)&buf1[lx] = z;  *(float4*)&buf1[65 * SWC + lx] = z;
    }
    __syncthreads();

    const bool wOK = (row >= 16) && (row < 48) && (seg >= 4) && (seg < 12);
    float* gbase = ys + (size_t)c0 * BHW_ + ((size_t)b * H_ + gy) * W_ + gx;

#pragma unroll
    for (int i = 0; i < CHUNK; ++i) {
        const float w0 = dw[i*9+0], w1 = dw[i*9+1], w2 = dw[i*9+2];
        const float w3 = dw[i*9+3], w4 = dw[i*9+4], w5 = dw[i*9+5];
        const float w6 = dw[i*9+6], w7 = dw[i*9+7], w8 = dw[i*9+8];

        float4 rT = *(const float4*)&cur[cell - SWC];
        float4 rM = *(const float4*)&cur[cell];
        float4 rB = *(const float4*)&cur[cell + SWC];

        float tl = dpp_row_shr1(rT.w), tr = dpp_row_shl1(rT.x);
        float ml = dpp_row_shr1(rM.w), mr = dpp_row_shl1(rM.x);
        float bl = dpp_row_shr1(rB.w), br = dpp_row_shl1(rB.x);

        float s0 = fmaf(tl,   w0, fmaf(rT.x, w1, fmaf(rT.y, w2,
                   fmaf(ml,   w3, fmaf(rM.x, w4, fmaf(rM.y, w5,
                   fmaf(bl,   w6, fmaf(rB.x, w7, rB.y * w8))))))));
        float s1 = fmaf(rT.x, w0, fmaf(rT.y, w1, fmaf(rT.z, w2,
                   fmaf(rM.x, w3, fmaf(rM.y, w4, fmaf(rM.z, w5,
                   fmaf(rB.x, w6, fmaf(rB.y, w7, rB.z * w8))))))));
        float s2 = fmaf(rT.y, w0, fmaf(rT.z, w1, fmaf(rT.w, w2,
                   fmaf(rM.y, w3, fmaf(rM.z, w4, fmaf(rM.w, w5,
                   fmaf(rB.y, w6, fmaf(rB.z, w7, rB.w * w8))))))));
        float s3 = fmaf(rT.z, w0, fmaf(rT.w, w1, fmaf(tr,   w2,
                   fmaf(rM.z, w3, fmaf(rM.w, w4, fmaf(mr,   w5,
                   fmaf(rB.z, w6, fmaf(rB.w, w7, br   * w8))))))));
        float4 ov;
        ov.x = fminf(fmaxf(s0, 0.f), 6.f) * msk;
        ov.y = fminf(fmaxf(s1, 0.f), 6.f) * msk;
        ov.z = fminf(fmaxf(s2, 0.f), 6.f) * msk;
        ov.w = fminf(fmaxf(s3, 0.f), 6.f) * msk;

        if (i < CHUNK - 1) {
            *(float4*)&nxt[cell] = ov;
            __syncthreads();
            float* tmp = cur; cur = nxt; nxt = tmp;
        }
        if (wOK)
            *(float4*)(gbase + (size_t)i * BHW_) = ov;
    }
}

// ---------------------------------------------------------------------------
// fuse_mfma: h = A·y as split-bf16 MFMA GEMM (3 cross products), then
// bias+clip+cw-dot epilogue. Per block: 4 waves; per tile: 64 px x 64 c.
// LDS: y staged as bf16 hi/lo planes, stride 88 (176 B, 16-aligned,
// conflict-free b128 phases). A frags resident in registers.
// ---------------------------------------------------------------------------
__global__ __launch_bounds__(256) void fuse_mfma(
    const float* __restrict__ ys,
    const float* __restrict__ pw_w,
    const float* __restrict__ gamma,
    const float* __restrict__ beta,
    const float* __restrict__ mean,
    const float* __restrict__ var,
    const float* __restrict__ conv_w,
    float* __restrict__ out)
{
    __shared__ short yh[64 * 88];
    __shared__ short yl[64 * 88];
    __shared__ float2 bc[P_];          // {bias, cw}

    const int tid  = threadIdx.x;
    const int lane = tid & 63;
    const int wv   = tid >> 6;         // 0..3
    const int nIdx = lane & 15;
    const int quad = lane >> 4;

    if (tid < P_) {
        float sc = gamma[tid] * rsqrtf(var[tid] + BN_EPS);
        bc[tid] = make_float2(beta[tid] - mean[tid] * sc, conv_w[tid]);
    }

    // Build A fragments: A[m=lane&15 -> p][k=quad*8+j -> c], BN-folded.
    bf16x8 Ah[4][2], Al[4][2];
#pragma unroll
    for (int pt = 0; pt < 4; ++pt) {
        const int p = pt * 16 + nIdx;
        const float sc = gamma[p] * rsqrtf(var[p] + BN_EPS);
#pragma unroll
        for (int kt = 0; kt < 2; ++kt) {
            const float* ap = pw_w + p * C_ + kt * 32 + quad * 8;
            bf16x8 hh, ll;
#pragma unroll
            for (int j = 0; j < 8; ++j) {
                float a = ap[j] * sc;
                short h = f2bf(a);
                hh[j] = h;
                ll[j] = f2bf(a - bf2f(h));
            }
            Ah[pt][kt] = hh;
            Al[pt][kt] = ll;
        }
    }
    __syncthreads();                   // bc visible

    const int px_ = tid & 63;          // staging: px this thread owns
    const int c0_ = (tid >> 6) * 16;   // staging: 16 channels this thread owns

    for (int tile = blockIdx.x; tile < BHW_ / 64; tile += gridDim.x) {
        const size_t base = (size_t)tile * 64;

        // global loads (coalesced along px; 16 channels per thread)
        float yv[16];
#pragma unroll
        for (int j = 0; j < 16; ++j)
            yv[j] = ys[(size_t)(c0_ + j) * BHW_ + base + px_];

        __syncthreads();               // prior tile's LDS fully consumed

        short hs[16], ls[16];
#pragma unroll
        for (int j = 0; j < 16; ++j) {
            short h = f2bf(yv[j]);
            hs[j] = h;
            ls[j] = f2bf(yv[j] - bf2f(h));
        }
        *(bf16x8*)&yh[px_ * 88 + c0_]     = *(bf16x8*)&hs[0];
        *(bf16x8*)&yh[px_ * 88 + c0_ + 8] = *(bf16x8*)&hs[8];
        *(bf16x8*)&yl[px_ * 88 + c0_]     = *(bf16x8*)&ls[0];
        *(bf16x8*)&yl[px_ * 88 + c0_ + 8] = *(bf16x8*)&ls[8];

        __syncthreads();

        f32x4 acc[4];
#pragma unroll
        for (int pt = 0; pt < 4; ++pt) acc[pt] = (f32x4){0.f, 0.f, 0.f, 0.f};

        const int col = wv * 16 + nIdx;
#pragma unroll
        for (int kt = 0; kt < 2; ++kt) {
            bf16x8 Bh = *(bf16x8*)&yh[col * 88 + kt * 32 + quad * 8];
            bf16x8 Bl = *(bf16x8*)&yl[col * 88 + kt * 32 + quad * 8];
#pragma unroll
            for (int pt = 0; pt < 4; ++pt) {
                acc[pt] = __builtin_amdgcn_mfma_f32_16x16x32_bf16(
                    Ah[pt][kt], Bh, acc[pt], 0, 0, 0);
                acc[pt] = __builtin_amdgcn_mfma_f32_16x16x32_bf16(
                    Ah[pt][kt], Bl, acc[pt], 0, 0, 0);
                acc[pt] = __builtin_amdgcn_mfma_f32_16x16x32_bf16(
                    Al[pt][kt], Bh, acc[pt], 0, 0, 0);
            }
        }

        // epilogue: D[m=quad*4+reg (+16*pt) -> p][n=lane&15 -> px]
        float sum = 0.f;
#pragma unroll
        for (int pt = 0; pt < 4; ++pt) {
#pragma unroll
            for (int r = 0; r < 4; ++r) {
                const int p = pt * 16 + quad * 4 + r;
                float2 b = bc[p];
                float v = fminf(fmaxf(acc[pt][r] + b.x, 0.f), 6.f);
                sum = fmaf(b.y, v, sum);
            }
        }
        sum += __shfl_xor(sum, 16, 64);
        sum += __shfl_xor(sum, 32, 64);
        if (lane < 16)
            out[base + wv * 16 + lane] = sum;
    }
}

// ---------------------------------------------------------------------------
extern "C" void kernel_launch(void* const* d_in, const int* in_sizes, int n_in,
                              void* d_out, int out_size, void* d_ws, size_t ws_size,
                              hipStream_t stream) {
    const float* x      = (const float*)d_in[0];
    const float* dw_w   = (const float*)d_in[1];
    const float* pw_w   = (const float*)d_in[2];
    const float* gamma  = (const float*)d_in[3];
    const float* beta   = (const float*)d_in[4];
    const float* mean   = (const float*)d_in[5];
    const float* var    = (const float*)d_in[6];
    const float* conv_w = (const float*)d_in[7];
    float* out = (float*)d_out;

    float* ys = (float*)d_ws;                      // (C, B, H, W) fp32 = 128 MiB

    dim3 cgrid(W_ / 32, H_ / 32, B_);              // 512 blocks

    chain_kernel<<<cgrid, 1024, 0, stream>>>(
        x, (size_t)C_ * H_ * W_, dw_w, ys, 0);
    for (int k = 1; k < C_ / CHUNK; ++k) {
        int c0 = k * CHUNK;
        chain_kernel<<<cgrid, 1024, 0, stream>>>(
            ys + (size_t)(c0 - 1) * BHW_, (size_t)H_ * W_,
            dw_w + c0 * 9, ys, c0);
    }

    fuse_mfma<<<1024, 256, 0, stream>>>(
        ys, pw_w, gamma, beta, mean, var, conv_w, out);
}

// Round 8
// 270.849 us; speedup vs baseline: 3.2217x; 1.0109x over previous
//
#include <hip/hip_runtime.h>
#include <hip/hip_bf16.h>

// Problem constants
#define B_    8
#define C_    64
#define P_    64
#define H_    256
#define W_    256
#define BHW_  (B_ * H_ * W_)   // 524288
#define BN_EPS 1e-5f

#define CHUNK 16
#define SWC   64               // chain LDS row stride (floats)

typedef _Float16 half4v __attribute__((ext_vector_type(4)));
typedef _Float16 half8v __attribute__((ext_vector_type(8)));
typedef _Float16 half2v __attribute__((ext_vector_type(2)));
typedef __attribute__((ext_vector_type(4))) float f32x4;

// DPP lane shifts within 16-lane rows (seg dimension = low 4 lane bits).
__device__ __forceinline__ float dpp_row_shr1(float v) {   // lane n <- n-1
    return __int_as_float(__builtin_amdgcn_update_dpp(
        0, __float_as_int(v), 0x111, 0xF, 0xF, true));
}
__device__ __forceinline__ float dpp_row_shl1(float v) {   // lane n <- n+1
    return __int_as_float(__builtin_amdgcn_update_dpp(
        0, __float_as_int(v), 0x101, 0xF, 0xF, true));
}

// ---------------------------------------------------------------------------
// Chain kernel with WAVE-LOCAL sync (no per-step __syncthreads).
// Wave w owns rows 4w..4w+3 of the 64x64 tile. Step i of wave w reads only
// rows 4w-1..4w+4 of state i-1 -> only waves w-1,w,w+1. Protocol:
//   write own rows (state i+1) -> threadfence_block -> prog[w]=i+1
//   spin until prog[w-1]>=i && prog[w+1]>=i before computing state i+1.
// prog[n]=s means wave n has (a) written its state-s rows and (b) finished
// all its reads of state s-1 -> the single >=i condition covers RAW and WAR.
// Output ys is fp16 (consumed by MFMA fuse); chain-internal state stays
// fp32; the next launch's seed channel is written fp32 to a side slab.
// ---------------------------------------------------------------------------
__global__ __launch_bounds__(1024, 8) void chain_kernel(
    const float* __restrict__ src,   // seed image slab base (fp32)
    size_t src_batch_stride,         // C_*H_*W_ for x, H_*W_ for seed slab
    const float* __restrict__ dw,    // dw_w + c0*9
    _Float16* __restrict__ ysh,      // fp16 ys base (C,B,H,W)
    float* __restrict__ seed_out,    // fp32 slab for next launch's seed (or null)
    int c0)
{
    __shared__ __align__(16) float buf0[66 * SWC];
    __shared__ __align__(16) float buf1[66 * SWC];
    __shared__ int prog[16];

    const int tid  = threadIdx.x;
    const int w    = tid >> 6;         // wave 0..15
    const int lane = tid & 63;
    const int row  = tid >> 4;         // 0..63 (= 4w + (lane>>4))
    const int seg  = tid & 15;
    const int lx   = seg * 4;
    const int b    = blockIdx.z;
    const int ty0  = blockIdx.y * 32;
    const int tx0  = blockIdx.x * 32;
    const int gy   = ty0 - 16 + row;
    const int gx   = tx0 - 16 + lx;
    const bool inImg = (gy >= 0) && (gy < H_) && (gx >= 0) && (gx < W_);
    const float msk = inImg ? 1.0f : 0.0f;
    const int cell = (row + 1) * SWC + lx;

    if (tid < 16) prog[tid] = 0;

    float4 v = make_float4(0.f, 0.f, 0.f, 0.f);
    if (inImg)
        v = *(const float4*)(src + (size_t)b * src_batch_stride
                             + (size_t)gy * W_ + gx);
    *(float4*)&buf0[cell] = v;
    if (row == 0) {                    // zero pad rows in both buffers
        float4 z = make_float4(0.f, 0.f, 0.f, 0.f);
        *(float4*)&buf0[lx] = z;  *(float4*)&buf0[65 * SWC + lx] = z;
        *(float4*)&buf1[lx] = z;  *(float4*)&buf1[65 * SWC + lx] = z;
    }
    __syncthreads();                   // the ONLY block-wide barrier

    volatile int* vp = prog;
    const int wm1 = (w == 0)  ? 0  : w - 1;
    const int wp1 = (w == 15) ? 15 : w + 1;

    const bool wOK = (row >= 16) && (row < 48) && (seg >= 4) && (seg < 12);
    const size_t goff = (size_t)(b * H_ + gy) * W_ + gx;   // valid when wOK
    _Float16* gb = ysh + (size_t)c0 * BHW_ + (wOK ? goff : 0);
    float* sb = seed_out ? seed_out + (wOK ? goff : 0) : nullptr;

#pragma unroll
    for (int i = 0; i < CHUNK; ++i) {
        const float w0 = dw[i*9+0], w1 = dw[i*9+1], w2 = dw[i*9+2];
        const float w3 = dw[i*9+3], w4 = dw[i*9+4], w5 = dw[i*9+5];
        const float w6 = dw[i*9+6], w7 = dw[i*9+7], w8 = dw[i*9+8];

        while (vp[wm1] < i || vp[wp1] < i) { /* spin: broadcast ds_read */ }

        float* cur = (i & 1) ? buf1 : buf0;
        float* nxt = (i & 1) ? buf0 : buf1;

        float4 rT = *(const float4*)&cur[cell - SWC];
        float4 rM = *(const float4*)&cur[cell];
        float4 rB = *(const float4*)&cur[cell + SWC];

        float tl = dpp_row_shr1(rT.w), tr = dpp_row_shl1(rT.x);
        float ml = dpp_row_shr1(rM.w), mr = dpp_row_shl1(rM.x);
        float bl = dpp_row_shr1(rB.w), br = dpp_row_shl1(rB.x);

        float s0 = fmaf(tl,   w0, fmaf(rT.x, w1, fmaf(rT.y, w2,
                   fmaf(ml,   w3, fmaf(rM.x, w4, fmaf(rM.y, w5,
                   fmaf(bl,   w6, fmaf(rB.x, w7, rB.y * w8))))))));
        float s1 = fmaf(rT.x, w0, fmaf(rT.y, w1, fmaf(rT.z, w2,
                   fmaf(rM.x, w3, fmaf(rM.y, w4, fmaf(rM.z, w5,
                   fmaf(rB.x, w6, fmaf(rB.y, w7, rB.z * w8))))))));
        float s2 = fmaf(rT.y, w0, fmaf(rT.z, w1, fmaf(rT.w, w2,
                   fmaf(rM.y, w3, fmaf(rM.z, w4, fmaf(rM.w, w5,
                   fmaf(rB.y, w6, fmaf(rB.z, w7, rB.w * w8))))))));
        float s3 = fmaf(rT.z, w0, fmaf(rT.w, w1, fmaf(tr,   w2,
                   fmaf(rM.z, w3, fmaf(rM.w, w4, fmaf(mr,   w5,
                   fmaf(rB.z, w6, fmaf(rB.w, w7, br   * w8))))))));
        float4 ov;
        ov.x = fminf(fmaxf(s0, 0.f), 6.f) * msk;
        ov.y = fminf(fmaxf(s1, 0.f), 6.f) * msk;
        ov.z = fminf(fmaxf(s2, 0.f), 6.f) * msk;
        ov.w = fminf(fmaxf(s3, 0.f), 6.f) * msk;

        if (i < CHUNK - 1) {
            *(float4*)&nxt[cell] = ov;
            __threadfence_block();             // data visible before flag
            if (lane == 0) vp[w] = i + 1;      // publish progress
        }

        if (wOK) {
            half4v hv;
            hv.x = (_Float16)ov.x; hv.y = (_Float16)ov.y;
            hv.z = (_Float16)ov.z; hv.w = (_Float16)ov.w;
            *(half4v*)(gb + (size_t)i * BHW_) = hv;
            if (i == CHUNK - 1 && sb)
                *(float4*)sb = ov;             // fp32 seed for next launch
        }
    }
}

// ---------------------------------------------------------------------------
// fuse_mfma (fp16 y): h = A*y via f16 MFMA, A split hi/lo fp16 (2 MFMAs per
// fragment pair), y single fp16 plane. Then bias+clip+cw-dot epilogue.
// ---------------------------------------------------------------------------
__global__ __launch_bounds__(256) void fuse_mfma(
    const _Float16* __restrict__ ysh,  // (C, BHW) fp16
    const float* __restrict__ pw_w,
    const float* __restrict__ gamma,
    const float* __restrict__ beta,
    const float* __restrict__ mean,
    const float* __restrict__ var,
    const float* __restrict__ conv_w,
    float* __restrict__ out)
{
    __shared__ _Float16 yt[64 * 88];   // [px][c], stride 88 (176 B)
    __shared__ float2 bc[P_];          // {bias, cw}

    const int tid  = threadIdx.x;
    const int lane = tid & 63;
    const int wv   = tid >> 6;         // 0..3
    const int nIdx = lane & 15;
    const int quad = lane >> 4;

    if (tid < P_) {
        float sc = gamma[tid] * rsqrtf(var[tid] + BN_EPS);
        bc[tid] = make_float2(beta[tid] - mean[tid] * sc, conv_w[tid]);
    }

    // A fragments: A[m=nIdx -> p (+16pt)][k=quad*8+j -> c (+32kt)], BN-folded,
    // split into fp16 hi + lo.
    half8v Ah[4][2], Al[4][2];
#pragma unroll
    for (int pt = 0; pt < 4; ++pt) {
        const int p = pt * 16 + nIdx;
        const float sc = gamma[p] * rsqrtf(var[p] + BN_EPS);
#pragma unroll
        for (int kt = 0; kt < 2; ++kt) {
            const float* ap = pw_w + p * C_ + kt * 32 + quad * 8;
            half8v hh, ll;
#pragma unroll
            for (int j = 0; j < 8; ++j) {
                float a = ap[j] * sc;
                _Float16 h = (_Float16)a;
                hh[j] = h;
                ll[j] = (_Float16)(a - (float)h);
            }
            Ah[pt][kt] = hh;
            Al[pt][kt] = ll;
        }
    }
    __syncthreads();                   // bc visible

    // staging mapping: thread owns 2 consecutive px and 8 channels
    const int px2 = (tid & 31) * 2;          // 0,2,..,62
    const int c8  = (tid >> 5) * 8;          // 0,8,..,56

    for (int tile = blockIdx.x; tile < BHW_ / 64; tile += gridDim.x) {
        const size_t base = (size_t)tile * 64;

        half2v yv[8];
#pragma unroll
        for (int j = 0; j < 8; ++j)
            yv[j] = *(const half2v*)(ysh + (size_t)(c8 + j) * BHW_ + base + px2);

        __syncthreads();               // prior tile fully consumed

        half8v e0, e1;
#pragma unroll
        for (int j = 0; j < 8; ++j) { e0[j] = yv[j].x; e1[j] = yv[j].y; }
        *(half8v*)&yt[px2 * 88 + c8]       = e0;
        *(half8v*)&yt[(px2 + 1) * 88 + c8] = e1;

        __syncthreads();

        f32x4 acc[4];
#pragma unroll
        for (int pt = 0; pt < 4; ++pt) acc[pt] = (f32x4){0.f, 0.f, 0.f, 0.f};

        const int col = wv * 16 + nIdx;
#pragma unroll
        for (int kt = 0; kt < 2; ++kt) {
            half8v Bv = *(half8v*)&yt[col * 88 + kt * 32 + quad * 8];
#pragma unroll
            for (int pt = 0; pt < 4; ++pt) {
                acc[pt] = __builtin_amdgcn_mfma_f32_16x16x32_f16(
                    Ah[pt][kt], Bv, acc[pt], 0, 0, 0);
                acc[pt] = __builtin_amdgcn_mfma_f32_16x16x32_f16(
                    Al[pt][kt], Bv, acc[pt], 0, 0, 0);
            }
        }

        // epilogue: D[m=quad*4+r (+16pt) -> p][n=nIdx -> px]
        float sum = 0.f;
#pragma unroll
        for (int pt = 0; pt < 4; ++pt) {
#pragma unroll
            for (int r = 0; r < 4; ++r) {
                const int p = pt * 16 + quad * 4 + r;
                float2 bcv = bc[p];
                float vv = fminf(fmaxf(acc[pt][r] + bcv.x, 0.f), 6.f);
                sum = fmaf(bcv.y, vv, sum);
            }
        }
        sum += __shfl_xor(sum, 16, 64);
        sum += __shfl_xor(sum, 32, 64);
        if (lane < 16)
            out[base + wv * 16 + lane] = sum;
    }
}

// ---------------------------------------------------------------------------
extern "C" void kernel_launch(void* const* d_in, const int* in_sizes, int n_in,
                              void* d_out, int out_size, void* d_ws, size_t ws_size,
                              hipStream_t stream) {
    const float* x      = (const float*)d_in[0];
    const float* dw_w   = (const float*)d_in[1];
    const float* pw_w   = (const float*)d_in[2];
    const float* gamma  = (const float*)d_in[3];
    const float* beta   = (const float*)d_in[4];
    const float* mean   = (const float*)d_in[5];
    const float* var    = (const float*)d_in[6];
    const float* conv_w = (const float*)d_in[7];
    float* out = (float*)d_out;

    _Float16* ysh = (_Float16*)d_ws;                       // 64 MiB fp16 ys
    float* seeds = (float*)((char*)d_ws + (size_t)C_ * BHW_ * sizeof(_Float16));
    // seeds: 3 fp32 slabs of BHW_ floats (channels 15, 31, 47)

    dim3 cgrid(W_ / 32, H_ / 32, B_);                      // 512 blocks

    chain_kernel<<<cgrid, 1024, 0, stream>>>(
        x, (size_t)C_ * H_ * W_, dw_w, ysh, seeds, 0);
    for (int k = 1; k < C_ / CHUNK; ++k) {
        float* seed_out = (k < 3) ? seeds + (size_t)k * BHW_ : nullptr;
        chain_kernel<<<cgrid, 1024, 0, stream>>>(
            seeds + (size_t)(k - 1) * BHW_, (size_t)H_ * W_,
            dw_w + k * CHUNK * 9, ysh, seed_out, k * CHUNK);
    }

    fuse_mfma<<<1024, 256, 0, stream>>>(
        ysh, pw_w, gamma, beta, mean, var, conv_w, out);
}